// Round 1
// baseline (2596.607 us; speedup 1.0000x reference)
//
#include <hip/hip_runtime.h>

#define N_SEQ 250000
#define LSEQ  40
#define CIN   20
#define KW    4
#define DCH   32
#define L1    37   // LSEQ - KW + 1
#define L2    34   // L1 - KW + 1
#define N_BAGS 100
#define SPB   2500 // sequences per bag (equal bags by construction)
#define S_BLK 6    // sequences per block in kernel 1
#define H1STR 36   // padded row stride for h1/h2 in LDS (16B aligned, breaks pow2)

__device__ __forceinline__ float selu_f(float x) {
  // jax.nn.selu constants
  float e = 1.6732632423543772f * (__expf(x) - 1.0f);
  return 1.0507009873554805f * ((x > 0.0f) ? x : e);
}

// Kernel 1: per-sequence CNN (conv1+SELU, conv2+SELU, maxpool) + attention MLP
// One thread computes one (sequence, position) with all 32 channels in registers.
// Weight indices are wave-uniform -> scalar loads (s_load), activations via LDS.
__global__ __launch_bounds__(256) void seq_kernel(
    const float* __restrict__ x,
    const float* __restrict__ w1, const float* __restrict__ b1,
    const float* __restrict__ w2, const float* __restrict__ b2,
    const float* __restrict__ aw1, const float* __restrict__ ab1,
    const float* __restrict__ aw2, const float* __restrict__ ab2,
    const float* __restrict__ aw3, const float* __restrict__ ab3,
    float* __restrict__ se_out, float* __restrict__ sc_out)
{
  __shared__ float h1s[S_BLK * L1 * H1STR];          // 31968 B
  __shared__ float uni[S_BLK * L2 * H1STR];          // overlay: xs (4800 f) then h2 (7344 f)
  __shared__ float sebuf[S_BLK * DCH];
  __shared__ float abuf[S_BLK * DCH];

  const int tid  = threadIdx.x;
  const int seq0 = blockIdx.x * S_BLK;
  const int svalid = min(S_BLK, N_SEQ - seq0);

  // ---- stage x into LDS (coalesced) ----
  float* xs = uni;
  const int xtot = svalid * LSEQ * CIN;
  for (int i = tid; i < xtot; i += 256)
    xs[i] = x[(size_t)seq0 * LSEQ * CIN + i];
  __syncthreads();

  // ---- conv1 + SELU ----
  if (tid < svalid * L1) {
    const int s = tid / L1, l = tid - s * L1;
    float acc[DCH];
    #pragma unroll
    for (int d = 0; d < DCH; d++) acc[d] = b1[d];
    for (int k = 0; k < KW; k++) {
      const float* wrow = &w1[k * CIN * DCH];
      const float* xrow = &xs[s * LSEQ * CIN + (l + k) * CIN];
      for (int c = 0; c < CIN; c++) {
        const float xv = xrow[c];
        #pragma unroll
        for (int d = 0; d < DCH; d++) acc[d] = fmaf(xv, wrow[c * DCH + d], acc[d]);
      }
    }
    float* hr = &h1s[tid * H1STR];  // tid == s*L1 + l
    #pragma unroll
    for (int d = 0; d < DCH; d++) hr[d] = selu_f(acc[d]);
  }
  __syncthreads();   // xs dead from here; reuse uni as h2

  // ---- conv2 + SELU ----
  float* h2s = uni;
  if (tid < svalid * L2) {
    const int s = tid / L2, l = tid - s * L2;
    float acc[DCH];
    #pragma unroll
    for (int d = 0; d < DCH; d++) acc[d] = b2[d];
    for (int k = 0; k < KW; k++) {
      const float* wrow = &w2[k * DCH * DCH];
      const float* hr   = &h1s[(s * L1 + l + k) * H1STR];
      for (int c = 0; c < DCH; c++) {
        const float hv = hr[c];
        #pragma unroll
        for (int d = 0; d < DCH; d++) acc[d] = fmaf(hv, wrow[c * DCH + d], acc[d]);
      }
    }
    float* orow = &h2s[tid * H1STR];  // tid == s*L2 + l
    #pragma unroll
    for (int d = 0; d < DCH; d++) orow[d] = selu_f(acc[d]);
  }
  __syncthreads();

  // ---- maxpool over positions ----
  if (tid < svalid * DCH) {
    const int s = tid >> 5, d = tid & 31;
    float m = -3.4e38f;
    for (int l = 0; l < L2; l++) m = fmaxf(m, h2s[(s * L2 + l) * H1STR + d]);
    sebuf[tid] = m;
    se_out[(size_t)seq0 * DCH + tid] = m;   // (seq0+s)*32 + d
  }
  __syncthreads();

  // ---- attention MLP layer 1 ----
  if (tid < svalid * DCH) {
    const int s = tid >> 5, d = tid & 31;
    float a = ab1[d];
    #pragma unroll
    for (int c = 0; c < DCH; c++) a = fmaf(sebuf[s * DCH + c], aw1[c * DCH + d], a);
    abuf[tid] = selu_f(a);
  }
  __syncthreads();

  // ---- attention MLP layer 2 + score reduction ----
  if (tid < svalid * DCH) {
    const int s = tid >> 5, d = tid & 31;
    float a = ab2[d];
    #pragma unroll
    for (int c = 0; c < DCH; c++) a = fmaf(abuf[s * DCH + c], aw2[c * DCH + d], a);
    a = selu_f(a);
    float p = a * aw3[d];
    #pragma unroll
    for (int off = 16; off > 0; off >>= 1) p += __shfl_xor(p, off, 32);
    if (d == 0) sc_out[seq0 + s] = p + ab3[0];
  }
}

// Kernel 2: per-bag segment softmax + weighted pooling + the two output MLPs.
// One block per bag (2500 sequences each).
__global__ __launch_bounds__(256) void bag_kernel(
    const float* __restrict__ se, const float* __restrict__ sc,
    const float* __restrict__ aw1, const float* __restrict__ ab1,
    const float* __restrict__ aw2, const float* __restrict__ ab2,
    const float* __restrict__ bw1, const float* __restrict__ bb1,
    const float* __restrict__ bw2, const float* __restrict__ bb2,
    float* __restrict__ out)
{
  const int bag = blockIdx.x, tid = threadIdx.x;
  const size_t base = (size_t)bag * SPB;

  __shared__ float pr[4][33];
  __shared__ float red[33];
  __shared__ float pool[DCH], hA[DCH], hB[DCH];

  // ---- phase 1: bag max of scores ----
  float m = -3.4e38f;
  for (int i = tid; i < SPB; i += 256) m = fmaxf(m, sc[base + i]);
  #pragma unroll
  for (int off = 32; off > 0; off >>= 1) m = fmaxf(m, __shfl_xor(m, off, 64));
  if ((tid & 63) == 0) pr[tid >> 6][0] = m;
  __syncthreads();
  const float bagmax = fmaxf(fmaxf(pr[0][0], pr[1][0]), fmaxf(pr[2][0], pr[3][0]));
  __syncthreads();  // pr reused below

  // ---- phase 2: sum(e) and sum(e * seq_embed) ----
  float acc[33];
  #pragma unroll
  for (int d = 0; d < 33; d++) acc[d] = 0.0f;
  for (int i = tid; i < SPB; i += 256) {
    const float e = __expf(sc[base + i] - bagmax);
    acc[32] += e;
    const float* sr = &se[(base + i) * DCH];
    #pragma unroll
    for (int d = 0; d < DCH; d++) acc[d] = fmaf(e, sr[d], acc[d]);
  }
  #pragma unroll
  for (int d = 0; d < 33; d++) {
    float v = acc[d];
    #pragma unroll
    for (int off = 32; off > 0; off >>= 1) v += __shfl_xor(v, off, 64);
    if ((tid & 63) == 0) pr[tid >> 6][d] = v;
  }
  __syncthreads();
  if (tid < 33) red[tid] = pr[0][tid] + pr[1][tid] + pr[2][tid] + pr[3][tid];
  __syncthreads();
  if (tid < DCH) pool[tid] = red[tid] / red[32];
  __syncthreads();

  // ---- output nets: hidden layer (SELU) ----
  if (tid < DCH) {
    float a = ab1[tid], b = bb1[tid];
    #pragma unroll
    for (int c = 0; c < DCH; c++) {
      a = fmaf(pool[c], aw1[c * DCH + tid], a);
      b = fmaf(pool[c], bw1[c * DCH + tid], b);
    }
    hA[tid] = selu_f(a);
    hB[tid] = selu_f(b);
  }
  __syncthreads();

  // ---- output nets: final layer + sigmoid ----
  if (tid < 21) {
    float v = ab2[tid];
    #pragma unroll
    for (int d = 0; d < DCH; d++) v = fmaf(hA[d], aw2[d * 21 + tid], v);
    out[bag * 21 + tid] = 1.0f / (1.0f + __expf(-v));
  } else if (tid >= 32 && tid < 72) {
    const int j = tid - 32;
    float v = bb2[j];
    #pragma unroll
    for (int d = 0; d < DCH; d++) v = fmaf(hB[d], bw2[d * 40 + j], v);
    out[N_BAGS * 21 + bag * 40 + j] = 1.0f / (1.0f + __expf(-v));
  }
}

extern "C" void kernel_launch(void* const* d_in, const int* in_sizes, int n_in,
                              void* d_out, int out_size, void* d_ws, size_t ws_size,
                              hipStream_t stream)
{
  const float* x    = (const float*)d_in[0];
  // d_in[1] = n_per_bag (int32): equal bags of SPB by construction, unused.
  const float* c1w  = (const float*)d_in[2];
  const float* c1b  = (const float*)d_in[3];
  const float* c2w  = (const float*)d_in[4];
  const float* c2b  = (const float*)d_in[5];
  const float* aw1  = (const float*)d_in[6];
  const float* ab1  = (const float*)d_in[7];
  const float* aw2  = (const float*)d_in[8];
  const float* ab2  = (const float*)d_in[9];
  const float* aw3  = (const float*)d_in[10];
  const float* ab3  = (const float*)d_in[11];
  const float* oaw1 = (const float*)d_in[12];
  const float* oab1 = (const float*)d_in[13];
  const float* oaw2 = (const float*)d_in[14];
  const float* oab2 = (const float*)d_in[15];
  const float* obw1 = (const float*)d_in[16];
  const float* obb1 = (const float*)d_in[17];
  const float* obw2 = (const float*)d_in[18];
  const float* obb2 = (const float*)d_in[19];
  float* out = (float*)d_out;

  // workspace: seq_embed (N_SEQ*32 f32) + scores (N_SEQ f32) = 33 MB
  float* se = (float*)d_ws;
  float* sc = se + (size_t)N_SEQ * DCH;

  const int nblk = (N_SEQ + S_BLK - 1) / S_BLK;
  seq_kernel<<<nblk, 256, 0, stream>>>(x, c1w, c1b, c2w, c2b,
                                       aw1, ab1, aw2, ab2, aw3, ab3, se, sc);
  bag_kernel<<<N_BAGS, 256, 0, stream>>>(se, sc, oaw1, oab1, oaw2, oab2,
                                         obw1, obb1, obw2, obb2, out);
}

// Round 2
// 1571.889 us; speedup vs baseline: 1.6519x; 1.6519x over previous
//
#include <hip/hip_runtime.h>

#define N_SEQ 250000
#define LSEQ  40
#define CIN   20
#define KW    4
#define DCH   32
#define L1    37   // LSEQ - KW + 1
#define L2    34   // L1 - KW + 1
#define N_BAGS 100
#define SPB   2500
#define S_BLK 8            // sequences per block (250000 % 8 == 0 -> no tail)
#define R1    (S_BLK * L1) // 296 conv1 output rows per block
#define R2    (S_BLK * L2) // 272 conv2 output rows per block (17 tiles exact)
#define T1    19           // ceil(296/16)
#define T2    17           // 272/16

typedef _Float16 f16;
typedef _Float16 f16x8 __attribute__((ext_vector_type(8)));
typedef _Float16 f16x4 __attribute__((ext_vector_type(4)));
typedef float    f32x4 __attribute__((ext_vector_type(4)));

__device__ __forceinline__ float selu_f(float x) {
  float e = 1.6732632423543772f * (__expf(x) - 1.0f);
  return 1.0507009873554805f * ((x > 0.0f) ? x : e);
}

// Kernel 1: f16-MFMA implicit-GEMM conv1+conv2 (+SELU), maxpool, attention MLP.
// Both convs are K=128 GEMMs (conv1 zero-padded from K=80). Weights live in
// VGPR B-fragments; activations in LDS, A-fragments via ds_read_b128.
__global__ __launch_bounds__(256) void seq_kernel(
    const float* __restrict__ x,
    const float* __restrict__ w1, const float* __restrict__ b1,
    const float* __restrict__ w2, const float* __restrict__ b2,
    const float* __restrict__ aw1, const float* __restrict__ ab1,
    const float* __restrict__ aw2, const float* __restrict__ ab2,
    const float* __restrict__ aw3, const float* __restrict__ ab3,
    float* __restrict__ se_out, float* __restrict__ sc_out)
{
  __shared__ __align__(16) f16 xs[S_BLK * LSEQ * DCH]; // 20480 B; reused as h2 (8704 elems)
  __shared__ __align__(16) f16 h1[S_BLK * L1 * DCH];   // 18944 B
  __shared__ float sebuf[S_BLK * DCH];
  __shared__ float abuf[S_BLK * DCH];

  const int tid  = threadIdx.x;
  const int lane = tid & 63;
  const int wave = tid >> 6;
  const int n0   = lane & 15;   // MFMA N / D-col index
  const int quad = lane >> 4;   // MFMA k-chunk selector

  const int seq0 = blockIdx.x * S_BLK;

  // ---- B fragments (weights) into VGPRs: B[k][n], lane holds n=lane&15(+16), k=quad*8+j ----
  f16x8 bf1[KW][2], bf2[KW][2];
  #pragma unroll
  for (int t = 0; t < KW; t++) {
    #pragma unroll
    for (int j = 0; j < 8; j++) {
      const int c = quad * 8 + j;                   // padded input-channel index
      float v0 = 0.0f, v1 = 0.0f;
      if (c < CIN) {
        v0 = w1[(t * CIN + c) * DCH + n0];
        v1 = w1[(t * CIN + c) * DCH + n0 + 16];
      }
      bf1[t][0][j] = (f16)v0;
      bf1[t][1][j] = (f16)v1;
      bf2[t][0][j] = (f16)w2[(t * DCH + c) * DCH + n0];
      bf2[t][1][j] = (f16)w2[(t * DCH + c) * DCH + n0 + 16];
    }
  }
  const float bias1a = b1[n0], bias1b = b1[n0 + 16];
  const float bias2a = b2[n0], bias2b = b2[n0 + 16];

  // ---- stage x -> LDS as f16, channels padded 20->32 with zeros ----
  {
    const f16x4 z4 = {(f16)0.f, (f16)0.f, (f16)0.f, (f16)0.f};
    for (int zi = tid; zi < S_BLK * LSEQ * 3; zi += 256) {   // 960 pad-chunks of 4
      const int row = zi / 3, part = zi - row * 3;
      *(f16x4*)&xs[row * DCH + CIN + part * 4] = z4;
    }
    const float4* xg = (const float4*)(x + (size_t)blockIdx.x * (S_BLK * LSEQ * CIN));
    for (int i = tid; i < S_BLK * LSEQ * CIN / 4; i += 256) { // 1600 float4
      const float4 v = xg[i];
      const int gf = i * 4;
      const int s = gf / (LSEQ * CIN);
      const int f = gf - s * (LSEQ * CIN);
      const int l = f / CIN, c = f - l * CIN;                 // c in {0,4,8,12,16}
      f16x4 h; h[0] = (f16)v.x; h[1] = (f16)v.y; h[2] = (f16)v.z; h[3] = (f16)v.w;
      *(f16x4*)&xs[(s * LSEQ + l) * DCH + c] = h;
    }
  }
  __syncthreads();

  // ---- conv1 (M=296, N=32, K=128) ----
  for (int tile = wave; tile < T1; tile += 4) {
    int r = tile * 16 + n0;
    const bool valid_a = (r < R1);
    if (!valid_a) r = 0;
    const int s = r / L1, l = r - s * L1;
    f32x4 c0 = {0.f, 0.f, 0.f, 0.f}, c1 = {0.f, 0.f, 0.f, 0.f};
    #pragma unroll
    for (int t = 0; t < KW; t++) {
      const f16x8 a = *(const f16x8*)&xs[((s * LSEQ + l + t) << 5) + (quad << 3)];
      c0 = __builtin_amdgcn_mfma_f32_16x16x32_f16(a, bf1[t][0], c0, 0, 0, 0);
      c1 = __builtin_amdgcn_mfma_f32_16x16x32_f16(a, bf1[t][1], c1, 0, 0, 0);
    }
    #pragma unroll
    for (int reg = 0; reg < 4; reg++) {
      const int rr = tile * 16 + quad * 4 + reg;   // D row = (lane>>4)*4 + reg
      if (rr < R1) {
        const int s2 = rr / L1, l2 = rr - s2 * L1;
        h1[((s2 * L1 + l2) << 5) + n0]      = (f16)selu_f(c0[reg] + bias1a);
        h1[((s2 * L1 + l2) << 5) + n0 + 16] = (f16)selu_f(c1[reg] + bias1b);
      }
    }
  }
  __syncthreads();

  // ---- conv2 (M=272, N=32, K=128); output h2 overlays xs ----
  f16* h2 = xs;
  for (int tile = wave; tile < T2; tile += 4) {
    const int r = tile * 16 + n0;
    const int s = r / L2, l = r - s * L2;
    f32x4 c0 = {0.f, 0.f, 0.f, 0.f}, c1 = {0.f, 0.f, 0.f, 0.f};
    #pragma unroll
    for (int t = 0; t < KW; t++) {
      const f16x8 a = *(const f16x8*)&h1[((s * L1 + l + t) << 5) + (quad << 3)];
      c0 = __builtin_amdgcn_mfma_f32_16x16x32_f16(a, bf2[t][0], c0, 0, 0, 0);
      c1 = __builtin_amdgcn_mfma_f32_16x16x32_f16(a, bf2[t][1], c1, 0, 0, 0);
    }
    #pragma unroll
    for (int reg = 0; reg < 4; reg++) {
      const int rr = tile * 16 + quad * 4 + reg;
      const int s2 = rr / L2, l2 = rr - s2 * L2;
      h2[((s2 * L2 + l2) << 5) + n0]      = (f16)selu_f(c0[reg] + bias2a);
      h2[((s2 * L2 + l2) << 5) + n0 + 16] = (f16)selu_f(c1[reg] + bias2b);
    }
  }
  __syncthreads();

  // ---- maxpool over positions: thread = (s, d) ----
  {
    const int s = tid >> 5, d = tid & 31;
    float m = -3.4e38f;
    for (int l = 0; l < L2; l++) m = fmaxf(m, (float)h2[((s * L2 + l) << 5) + d]);
    sebuf[tid] = m;
    se_out[(size_t)seq0 * DCH + tid] = m;
  }
  __syncthreads();

  // ---- attention MLP layer 1 ----
  {
    const int s = tid >> 5, d = tid & 31;
    float a = ab1[d];
    #pragma unroll
    for (int c = 0; c < DCH; c++) a = fmaf(sebuf[s * DCH + c], aw1[c * DCH + d], a);
    abuf[tid] = selu_f(a);
  }
  __syncthreads();

  // ---- attention MLP layer 2 + score ----
  {
    const int s = tid >> 5, d = tid & 31;
    float a = ab2[d];
    #pragma unroll
    for (int c = 0; c < DCH; c++) a = fmaf(abuf[s * DCH + c], aw2[c * DCH + d], a);
    a = selu_f(a);
    float p = a * aw3[d];
    #pragma unroll
    for (int off = 16; off > 0; off >>= 1) p += __shfl_xor(p, off, 32);
    if (d == 0) sc_out[seq0 + s] = p + ab3[0];
  }
}

// Kernel 2: per-bag segment softmax + weighted pooling + output MLPs (unchanged).
__global__ __launch_bounds__(256) void bag_kernel(
    const float* __restrict__ se, const float* __restrict__ sc,
    const float* __restrict__ aw1, const float* __restrict__ ab1,
    const float* __restrict__ aw2, const float* __restrict__ ab2,
    const float* __restrict__ bw1, const float* __restrict__ bb1,
    const float* __restrict__ bw2, const float* __restrict__ bb2,
    float* __restrict__ out)
{
  const int bag = blockIdx.x, tid = threadIdx.x;
  const size_t base = (size_t)bag * SPB;

  __shared__ float pr[4][33];
  __shared__ float red[33];
  __shared__ float pool[DCH], hA[DCH], hB[DCH];

  float m = -3.4e38f;
  for (int i = tid; i < SPB; i += 256) m = fmaxf(m, sc[base + i]);
  #pragma unroll
  for (int off = 32; off > 0; off >>= 1) m = fmaxf(m, __shfl_xor(m, off, 64));
  if ((tid & 63) == 0) pr[tid >> 6][0] = m;
  __syncthreads();
  const float bagmax = fmaxf(fmaxf(pr[0][0], pr[1][0]), fmaxf(pr[2][0], pr[3][0]));
  __syncthreads();

  float acc[33];
  #pragma unroll
  for (int d = 0; d < 33; d++) acc[d] = 0.0f;
  for (int i = tid; i < SPB; i += 256) {
    const float e = __expf(sc[base + i] - bagmax);
    acc[32] += e;
    const float* sr = &se[(base + i) * DCH];
    #pragma unroll
    for (int d = 0; d < DCH; d++) acc[d] = fmaf(e, sr[d], acc[d]);
  }
  #pragma unroll
  for (int d = 0; d < 33; d++) {
    float v = acc[d];
    #pragma unroll
    for (int off = 32; off > 0; off >>= 1) v += __shfl_xor(v, off, 64);
    if ((tid & 63) == 0) pr[tid >> 6][d] = v;
  }
  __syncthreads();
  if (tid < 33) red[tid] = pr[0][tid] + pr[1][tid] + pr[2][tid] + pr[3][tid];
  __syncthreads();
  if (tid < DCH) pool[tid] = red[tid] / red[32];
  __syncthreads();

  if (tid < DCH) {
    float a = ab1[tid], b = bb1[tid];
    #pragma unroll
    for (int c = 0; c < DCH; c++) {
      a = fmaf(pool[c], aw1[c * DCH + tid], a);
      b = fmaf(pool[c], bw1[c * DCH + tid], b);
    }
    hA[tid] = selu_f(a);
    hB[tid] = selu_f(b);
  }
  __syncthreads();

  if (tid < 21) {
    float v = ab2[tid];
    #pragma unroll
    for (int d = 0; d < DCH; d++) v = fmaf(hA[d], aw2[d * 21 + tid], v);
    out[bag * 21 + tid] = 1.0f / (1.0f + __expf(-v));
  } else if (tid >= 32 && tid < 72) {
    const int j = tid - 32;
    float v = bb2[j];
    #pragma unroll
    for (int d = 0; d < DCH; d++) v = fmaf(hB[d], bw2[d * 40 + j], v);
    out[N_BAGS * 21 + bag * 40 + j] = 1.0f / (1.0f + __expf(-v));
  }
}

extern "C" void kernel_launch(void* const* d_in, const int* in_sizes, int n_in,
                              void* d_out, int out_size, void* d_ws, size_t ws_size,
                              hipStream_t stream)
{
  const float* x    = (const float*)d_in[0];
  const float* c1w  = (const float*)d_in[2];
  const float* c1b  = (const float*)d_in[3];
  const float* c2w  = (const float*)d_in[4];
  const float* c2b  = (const float*)d_in[5];
  const float* aw1  = (const float*)d_in[6];
  const float* ab1  = (const float*)d_in[7];
  const float* aw2  = (const float*)d_in[8];
  const float* ab2  = (const float*)d_in[9];
  const float* aw3  = (const float*)d_in[10];
  const float* ab3  = (const float*)d_in[11];
  const float* oaw1 = (const float*)d_in[12];
  const float* oab1 = (const float*)d_in[13];
  const float* oaw2 = (const float*)d_in[14];
  const float* oab2 = (const float*)d_in[15];
  const float* obw1 = (const float*)d_in[16];
  const float* obb1 = (const float*)d_in[17];
  const float* obw2 = (const float*)d_in[18];
  const float* obb2 = (const float*)d_in[19];
  float* out = (float*)d_out;

  float* se = (float*)d_ws;                 // N_SEQ*32 f32
  float* sc = se + (size_t)N_SEQ * DCH;     // N_SEQ f32

  const int nblk = N_SEQ / S_BLK;           // 31250, exact
  seq_kernel<<<nblk, 256, 0, stream>>>(x, c1w, c1b, c2w, c2b,
                                       aw1, ab1, aw2, ab2, aw3, ab3, se, sc);
  bag_kernel<<<N_BAGS, 256, 0, stream>>>(se, sc, oaw1, oab1, oaw2, oab2,
                                         obw1, obb1, obw2, obb2, out);
}

// Round 3
// 1436.488 us; speedup vs baseline: 1.8076x; 1.0943x over previous
//
#include <hip/hip_runtime.h>

#define N_SEQ 250000
#define LSEQ  40
#define CIN   20
#define KW    4
#define DCH   32
#define L1    37   // LSEQ - KW + 1
#define L2    34   // L1 - KW + 1
#define N_BAGS 100
#define SPB   2500
#define S_BLK 8
#define R1    (S_BLK * L1)   // 296 conv1 output rows / block
#define R2    (S_BLK * L2)   // 272 conv2 output rows / block
#define T1C   10             // ceil(296/32) tiles of 32 rows
#define T2C   9              // ceil(272/32)
#define H1S   36             // h1 LDS row stride (f16 elems): 72 B -> 2-way-free b64 reads
#define H2S   33             // h2 LDS row stride: 66 B (scalar maxpool reads only)

typedef _Float16 f16;
typedef _Float16 f16x8 __attribute__((ext_vector_type(8)));
typedef _Float16 f16x4 __attribute__((ext_vector_type(4)));
typedef float    f32x16 __attribute__((ext_vector_type(16)));

__device__ __forceinline__ float selu_f(float x) {
  float e = 1.6732632423543772f * (__expf(x) - 1.0f);
  return 1.0507009873554805f * ((x > 0.0f) ? x : e);
}

// ---- prep: transpose+convert weights once per launch (1 block, ~2 us) ----
// w1T[n*80+k]  = f16(w1[k*32+n])  (k = t*20+c, K=80)
// w2T[n*128+k] = f16(w2[k*32+n])  (k = t*32+c, K=128)
// awT[d*32+c]  = aw[c*32+d]       (f32, for vectorized VALU MLP)
__global__ __launch_bounds__(256) void prep_kernel(
    const float* __restrict__ w1, const float* __restrict__ w2,
    const float* __restrict__ aw1, const float* __restrict__ aw2,
    f16* __restrict__ w1T, f16* __restrict__ w2T,
    float* __restrict__ aw1T, float* __restrict__ aw2T)
{
  const int tid = threadIdx.x;
  for (int i = tid; i < 32 * 80; i += 256) {
    const int n = i / 80, k = i - n * 80;
    w1T[i] = (f16)w1[k * 32 + n];
  }
  for (int i = tid; i < 32 * 128; i += 256) {
    const int n = i >> 7, k = i & 127;
    w2T[i] = (f16)w2[k * 32 + n];
  }
  for (int i = tid; i < 1024; i += 256) {
    const int d = i >> 5, c = i & 31;
    aw1T[i] = aw1[c * 32 + d];
    aw2T[i] = aw2[c * 32 + d];
  }
}

// ---- kernel 1: CNN via 32x32x16 f16 MFMA implicit-GEMM + maxpool + attention ----
__global__ __launch_bounds__(256, 4) void seq_kernel(
    const float* __restrict__ x,
    const f16*  __restrict__ w1T, const float* __restrict__ b1,
    const f16*  __restrict__ w2T, const float* __restrict__ b2,
    const float* __restrict__ aw1T, const float* __restrict__ ab1,
    const float* __restrict__ aw2T, const float* __restrict__ ab2,
    const float* __restrict__ aw3, const float* __restrict__ ab3,
    f16* __restrict__ se_out, float* __restrict__ sc_out)
{
  // region1: xs (6400 f16 flat copy of x, rows=20ch/40B) then h2 (272 rows x 33)
  // region2: h1 (296 rows x 36) then sebuf/abuf overlay
  __shared__ __align__(16) f16 reg1[R2 * H2S];   // 8976 f16 = 17952 B
  __shared__ __align__(16) f16 reg2[R1 * H1S];   // 10656 f16 = 21312 B

  f16* xs = reg1;
  f16* h2 = reg1;
  f16* h1 = reg2;
  float* sebuf = (float*)reg2;        // valid after conv2 barrier (h1 dead)
  float* abuf  = sebuf + 256;

  const int tid  = threadIdx.x;
  const int lane = tid & 63;
  const int wave = tid >> 6;
  const int m    = lane & 31;    // MFMA row (A) / col (C,D) index
  const int half = lane >> 5;    // MFMA k-half selector
  const int seq0 = blockIdx.x * S_BLK;

  // ---- B fragments from pre-transposed f16 weights: 13 x 16B loads ----
  // B[k = kc*16 + half*8 + j][n = m]
  f16x8 bf1[5], bf2[8];
  {
    const f16x8* w1t8 = (const f16x8*)w1T;   // elem (n*80 + kc*16 + half*8)/8
    const f16x8* w2t8 = (const f16x8*)w2T;   // elem (n*128 + kc*16 + half*8)/8
    #pragma unroll
    for (int kc = 0; kc < 5; kc++) bf1[kc] = w1t8[m * 10 + kc * 2 + half];
    #pragma unroll
    for (int kc = 0; kc < 8; kc++) bf2[kc] = w2t8[m * 16 + kc * 2 + half];
  }
  const float b1v = b1[m], b2v = b2[m];

  // ---- stage x -> LDS f16, flat copy (im2col rows are contiguous slices) ----
  {
    const float4* xg = (const float4*)(x + (size_t)blockIdx.x * (S_BLK * LSEQ * CIN));
    for (int i = tid; i < S_BLK * LSEQ * CIN / 4; i += 256) {   // 1600 float4
      const float4 v = xg[i];
      f16x4 h; h[0] = (f16)v.x; h[1] = (f16)v.y; h[2] = (f16)v.z; h[3] = (f16)v.w;
      *(f16x4*)&xs[i * 4] = h;
    }
  }
  __syncthreads();

  // ---- conv1: M=296 N=32 K=80 (exact), A row = xs[(s*40+l)*20 .. +80) ----
  for (int tile = wave; tile < T1C; tile += 4) {
    const unsigned r  = tile * 32 + m;
    const unsigned rc = (r < R1) ? r : (R1 - 1);
    const unsigned s  = rc / L1, l = rc - s * L1;
    const f16* arow = &xs[(s * LSEQ + l) * CIN];
    f32x16 acc;
    #pragma unroll
    for (int i = 0; i < 16; i++) acc[i] = b1v;
    #pragma unroll
    for (int kc = 0; kc < 5; kc++) {
      const int e = kc * 16 + half * 8;
      const f16x4 p0 = *(const f16x4*)(arow + e);
      const f16x4 p1 = *(const f16x4*)(arow + e + 4);
      const f16x8 a = __builtin_shufflevector(p0, p1, 0, 1, 2, 3, 4, 5, 6, 7);
      acc = __builtin_amdgcn_mfma_f32_32x32x16_f16(a, bf1[kc], acc, 0, 0, 0);
    }
    #pragma unroll
    for (int reg = 0; reg < 16; reg++) {
      const int rr = tile * 32 + (reg & 3) + 8 * (reg >> 2) + 4 * half;
      if (rr < R1) h1[rr * H1S + m] = (f16)selu_f(acc[reg]);
    }
  }
  __syncthreads();

  // ---- conv2: M=272 N=32 K=128, A row = h1 rows r..r+3 (stride H1S) ----
  // raw output (no SELU: selu(max) == max(selu) since SELU is monotone)
  for (int tile = wave; tile < T2C; tile += 4) {
    const unsigned r  = tile * 32 + m;
    const unsigned rc = (r < R2) ? r : (R2 - 1);
    const unsigned s  = rc / L2, l = rc - s * L2;
    const f16* abase = &h1[(s * L1 + l) * H1S];
    f32x16 acc;
    #pragma unroll
    for (int i = 0; i < 16; i++) acc[i] = b2v;
    #pragma unroll
    for (int kc = 0; kc < 8; kc++) {
      const int e = (kc >> 1) * H1S + (kc & 1) * 16 + half * 8;
      const f16x4 p0 = *(const f16x4*)(abase + e);
      const f16x4 p1 = *(const f16x4*)(abase + e + 4);
      const f16x8 a = __builtin_shufflevector(p0, p1, 0, 1, 2, 3, 4, 5, 6, 7);
      acc = __builtin_amdgcn_mfma_f32_32x32x16_f16(a, bf2[kc], acc, 0, 0, 0);
    }
    #pragma unroll
    for (int reg = 0; reg < 16; reg++) {
      const int rr = tile * 32 + (reg & 3) + 8 * (reg >> 2) + 4 * half;
      if (rr < R2) h2[rr * H2S + m] = (f16)acc[reg];
    }
  }
  __syncthreads();

  // ---- maxpool over positions, then single SELU ----
  {
    const int s = tid >> 5, d = tid & 31;
    float mx = -3.4e38f;
    for (int l = 0; l < L2; l++) mx = fmaxf(mx, (float)h2[(s * L2 + l) * H2S + d]);
    const float sv = selu_f(mx);
    sebuf[tid] = sv;
    se_out[(size_t)seq0 * DCH + tid] = (f16)sv;
  }
  __syncthreads();

  // ---- attention MLP layer 1 (vectorized weight loads from aw1T) ----
  {
    const int s = tid >> 5, d = tid & 31;
    const float4* wt = (const float4*)aw1T;   // elem d*32+c
    float a = ab1[d];
    #pragma unroll
    for (int c4 = 0; c4 < 8; c4++) {
      const float4 w = wt[d * 8 + c4];
      const float* sb = &sebuf[s * DCH + c4 * 4];
      a = fmaf(sb[0], w.x, a); a = fmaf(sb[1], w.y, a);
      a = fmaf(sb[2], w.z, a); a = fmaf(sb[3], w.w, a);
    }
    abuf[tid] = selu_f(a);
  }
  __syncthreads();

  // ---- attention MLP layer 2 + score ----
  {
    const int s = tid >> 5, d = tid & 31;
    const float4* wt = (const float4*)aw2T;
    float a = ab2[d];
    #pragma unroll
    for (int c4 = 0; c4 < 8; c4++) {
      const float4 w = wt[d * 8 + c4];
      const float* sb = &abuf[s * DCH + c4 * 4];
      a = fmaf(sb[0], w.x, a); a = fmaf(sb[1], w.y, a);
      a = fmaf(sb[2], w.z, a); a = fmaf(sb[3], w.w, a);
    }
    a = selu_f(a);
    float p = a * aw3[d];
    #pragma unroll
    for (int off = 16; off > 0; off >>= 1) p += __shfl_xor(p, off, 32);
    if (d == 0) sc_out[seq0 + s] = p + ab3[0];
  }
}

// ---- kernel 2: per-bag softmax pooling + output MLPs (se now f16) ----
__global__ __launch_bounds__(256) void bag_kernel(
    const f16* __restrict__ se, const float* __restrict__ sc,
    const float* __restrict__ aw1, const float* __restrict__ ab1,
    const float* __restrict__ aw2, const float* __restrict__ ab2,
    const float* __restrict__ bw1, const float* __restrict__ bb1,
    const float* __restrict__ bw2, const float* __restrict__ bb2,
    float* __restrict__ out)
{
  const int bag = blockIdx.x, tid = threadIdx.x;
  const size_t base = (size_t)bag * SPB;

  __shared__ float pr[4][33];
  __shared__ float red[33];
  __shared__ float pool[DCH], hA[DCH], hB[DCH];

  float m = -3.4e38f;
  for (int i = tid; i < SPB; i += 256) m = fmaxf(m, sc[base + i]);
  #pragma unroll
  for (int off = 32; off > 0; off >>= 1) m = fmaxf(m, __shfl_xor(m, off, 64));
  if ((tid & 63) == 0) pr[tid >> 6][0] = m;
  __syncthreads();
  const float bagmax = fmaxf(fmaxf(pr[0][0], pr[1][0]), fmaxf(pr[2][0], pr[3][0]));
  __syncthreads();

  float acc[33];
  #pragma unroll
  for (int d = 0; d < 33; d++) acc[d] = 0.0f;
  for (int i = tid; i < SPB; i += 256) {
    const float e = __expf(sc[base + i] - bagmax);
    acc[32] += e;
    const f16* sr = &se[(base + i) * DCH];
    #pragma unroll
    for (int q = 0; q < 8; q++) {
      const f16x4 v = *(const f16x4*)(sr + q * 4);
      #pragma unroll
      for (int j = 0; j < 4; j++) acc[q * 4 + j] = fmaf(e, (float)v[j], acc[q * 4 + j]);
    }
  }
  #pragma unroll
  for (int d = 0; d < 33; d++) {
    float v = acc[d];
    #pragma unroll
    for (int off = 32; off > 0; off >>= 1) v += __shfl_xor(v, off, 64);
    if ((tid & 63) == 0) pr[tid >> 6][d] = v;
  }
  __syncthreads();
  if (tid < 33) red[tid] = pr[0][tid] + pr[1][tid] + pr[2][tid] + pr[3][tid];
  __syncthreads();
  if (tid < DCH) pool[tid] = red[tid] / red[32];
  __syncthreads();

  if (tid < DCH) {
    float a = ab1[tid], b = bb1[tid];
    #pragma unroll
    for (int c = 0; c < DCH; c++) {
      a = fmaf(pool[c], aw1[c * DCH + tid], a);
      b = fmaf(pool[c], bw1[c * DCH + tid], b);
    }
    hA[tid] = selu_f(a);
    hB[tid] = selu_f(b);
  }
  __syncthreads();

  if (tid < 21) {
    float v = ab2[tid];
    #pragma unroll
    for (int d = 0; d < DCH; d++) v = fmaf(hA[d], aw2[d * 21 + tid], v);
    out[bag * 21 + tid] = 1.0f / (1.0f + __expf(-v));
  } else if (tid >= 32 && tid < 72) {
    const int j = tid - 32;
    float v = bb2[j];
    #pragma unroll
    for (int d = 0; d < DCH; d++) v = fmaf(hB[d], bw2[d * 40 + j], v);
    out[N_BAGS * 21 + bag * 40 + j] = 1.0f / (1.0f + __expf(-v));
  }
}

extern "C" void kernel_launch(void* const* d_in, const int* in_sizes, int n_in,
                              void* d_out, int out_size, void* d_ws, size_t ws_size,
                              hipStream_t stream)
{
  const float* x    = (const float*)d_in[0];
  const float* c1w  = (const float*)d_in[2];
  const float* c1b  = (const float*)d_in[3];
  const float* c2w  = (const float*)d_in[4];
  const float* c2b  = (const float*)d_in[5];
  const float* aw1  = (const float*)d_in[6];
  const float* ab1  = (const float*)d_in[7];
  const float* aw2  = (const float*)d_in[8];
  const float* ab2  = (const float*)d_in[9];
  const float* aw3  = (const float*)d_in[10];
  const float* ab3  = (const float*)d_in[11];
  const float* oaw1 = (const float*)d_in[12];
  const float* oab1 = (const float*)d_in[13];
  const float* oaw2 = (const float*)d_in[14];
  const float* oab2 = (const float*)d_in[15];
  const float* obw1 = (const float*)d_in[16];
  const float* obb1 = (const float*)d_in[17];
  const float* obw2 = (const float*)d_in[18];
  const float* obb2 = (const float*)d_in[19];
  float* out = (float*)d_out;

  // ws layout: seh f16 (16 MB) | sc f32 (1 MB) | w1T/w2T f16 | aw1T/aw2T f32
  char* ws = (char*)d_ws;
  f16*   seh  = (f16*)ws;                                   // 8,000,000 f16
  float* sc   = (float*)(ws + (size_t)16000000);            // 250,000 f32
  f16*   w1T  = (f16*)(ws + (size_t)17000000);              // 2560 f16
  f16*   w2T  = w1T + 2560 + 2560;                          // pad to keep 16B align; 4096 f16
  float* aw1T = (float*)(ws + (size_t)17000000 + 32768);    // 1024 f32
  float* aw2T = aw1T + 1024;

  prep_kernel<<<1, 256, 0, stream>>>(c1w, c2w, aw1, aw2, w1T, w2T, aw1T, aw2T);
  seq_kernel<<<N_SEQ / S_BLK, 256, 0, stream>>>(x, w1T, c1b, w2T, c2b,
                                                aw1T, ab1, aw2T, ab2, aw3, ab3,
                                                seh, sc);
  bag_kernel<<<N_BAGS, 256, 0, stream>>>(seh, sc, oaw1, oab1, oaw2, oab2,
                                         obw1, obb1, obw2, obb2, out);
}